// Round 14
// baseline (383.246 us; speedup 1.0000x reference)
//
#include <hip/hip_runtime.h>

#define S     2048
#define D     64
#define NH    12
#define NB    2
#define NBH   (NB*NH)       // 24
#define OUTSZ ((size_t)NBH*S*D)

#define BQ    32
#define QT    (S/BQ)        // 64
#define NBLK  (NBH*QT)      // 1536  (fallback grid)

#define BQ2   16
#define QT2   (S/BQ2)       // 128
#define NBLK2 (NBH*QT2)     // 3072

// workspace layout (bytes): converted operands only
#define KF_OFF    0
#define KF_SZ     ((size_t)NBH*S*128*2)        // 12582912 (fragment-ordered K)
#define VF_OFF    (KF_OFF + KF_SZ)
#define VF_SZ     ((size_t)2*NBH*D*S*2)        // 12582912 (fragment-ordered V)
#define MQ_OFF    (VF_OFF + VF_SZ)
#define MQ_SZ     ((size_t)NB*QT*S*4)          // 1048576 (32-row bitmasks)
#define WS_NEED   (MQ_OFF + MQ_SZ)             // 26214400

// fused conv grid partition
#define CK_BLKS   3072
#define CV_BLKS   (2*NBH*32)                   // 1536
#define CM_BLKS   (NB*QT)                      // 128
#define CONV_BLKS (CK_BLKS + CV_BLKS + CM_BLKS)

typedef __attribute__((ext_vector_type(8))) short short8;
typedef __attribute__((ext_vector_type(4))) float f32x4;

__device__ __forceinline__ unsigned short f2bf(float x){
  unsigned u = __builtin_bit_cast(unsigned, x);
  u += 0x7fffu + ((u >> 16) & 1u);       // RTNE
  return (unsigned short)(u >> 16);
}
__device__ __forceinline__ float bf2f(unsigned short h){
  unsigned u = ((unsigned)h) << 16;
  return __builtin_bit_cast(float, u);
}
__device__ __forceinline__ short8 pack8(const float4& a, const float4& b, float sc){
  short8 r;
  r[0]=(short)f2bf(a.x*sc); r[1]=(short)f2bf(a.y*sc);
  r[2]=(short)f2bf(a.z*sc); r[3]=(short)f2bf(a.w*sc);
  r[4]=(short)f2bf(b.x*sc); r[5]=(short)f2bf(b.y*sc);
  r[6]=(short)f2bf(b.z*sc); r[7]=(short)f2bf(b.w*sc);
  return r;
}
__device__ __forceinline__ int eoff(int row, int key){
  return ((row << 12) | (key << 1)) ^ ((row & 7) << 4);
}

// ------- fused conversions: K->kf frag order, V->vf frag order, mask->bitmask ----
__global__ __launch_bounds__(256) void conv_all(
    const float* __restrict__ kr, const float* __restrict__ ki,
    const float* __restrict__ vr, const float* __restrict__ vi,
    const int*   __restrict__ mask,
    unsigned short* __restrict__ kf, unsigned short* __restrict__ vf,
    unsigned* __restrict__ mq)
{
  __shared__ __align__(4) unsigned short tile[64][65];   // conv_v transpose tile
  int blk = blockIdx.x;
  int t   = threadIdx.x;

  if (blk < CK_BLKS){
    // K -> kf[bh][grp64][eo2][kc4][lane64][8]
    int idx  = blk*256 + t;
    int lane = idx & 63;
    int kc   = (idx >> 6) & 3;
    int eo   = (idx >> 8) & 1;
    int grp  = (idx >> 9) & 63;
    int bh   = idx >> 15;
    int key  = grp*32 + 2*(lane & 15) + eo;
    int d0   = kc*32 + (lane >> 4)*8;
    const float* src = (d0 < 64) ? kr + ((size_t)bh*S + key)*64 + d0
                                 : ki + ((size_t)bh*S + key)*64 + (d0 - 64);
    float4 a = *(const float4*)(src);
    float4 b = *(const float4*)(src + 4);
    *(short8*)(kf + (size_t)idx*8) = pack8(a, b, 1.f);
  } else if (blk < CK_BLKS + CV_BLKS){
    // V -> vf[ri*NBH+bh][dg4][c64][lane64][8]
    int bid = blk - CK_BLKS;
    int ri  = bid / (NBH*32);
    int rem = bid % (NBH*32);
    int bh  = rem / 32;
    int s0  = (rem % 32) * 64;
    const float* vp = (ri ? vi : vr) + (size_t)bh*S*D;
    #pragma unroll
    for (int it = 0; it < 4; it++){
      int row = (t >> 4) + it*16;                // s_local
      int c4  = (t & 15) * 4;                    // d
      float4 v = *(const float4*)(vp + (size_t)(s0+row)*D + c4);
      tile[c4+0][row] = f2bf(v.x);
      tile[c4+1][row] = f2bf(v.y);
      tile[c4+2][row] = f2bf(v.z);
      tile[c4+3][row] = f2bf(v.w);
    }
    __syncthreads();
    unsigned short* dst = vf + (size_t)(ri*NBH + bh) * 4*64*64*8;
    #pragma unroll
    for (int u = 0; u < 2; u++){
      int comb = u*256 + t;
      int lane = comb & 63;
      int cp   = (comb >> 6) & 1;
      int dg   = comb >> 7;
      int c    = s0/32 + cp;
      int d    = dg*16 + (lane & 15);
      int sl   = cp*32 + (lane >> 4)*8;
      short8 o;
      #pragma unroll
      for (int j = 0; j < 8; j++) o[j] = (short)tile[d][sl + j];
      *(short8*)(dst + (((size_t)dg*64 + c)*64 + lane)*8) = o;
    }
  } else {
    // mask -> mq[b][qt32][key] bitmask of 32 q-rows
    int bid = blk - CK_BLKS - CV_BLKS;
    int b   = bid >> 6;
    int qt  = bid & 63;
    int qbase = qt * BQ;
    #pragma unroll
    for (int it = 0; it < 8; it++){
      int key = it*256 + t;
      unsigned bits = 0;
      #pragma unroll
      for (int j = 0; j < 32; j++)
        bits |= (mask[((size_t)b*S + qbase + j)*S + key] ? 1u : 0u) << j;
      mq[((size_t)b*64 + qt)*S + key] = bits;
    }
  }
}

// ---- merged kernel v5: v4 + phase C folded into phase B writer waves ----
#define ESTRIDE 4144   // 2048 keys * 2B + 48B pad

__global__ __launch_bounds__(512) void cattn_merged(
    const float* __restrict__ q_real, const float* __restrict__ q_imag,
    const unsigned short* __restrict__ kf,
    const unsigned short* __restrict__ vf,
    const unsigned* __restrict__ mq,
    float* __restrict__ out)
{
  __shared__ __align__(16) char elds[BQ2*ESTRIDE];   // 66304 B
  __shared__ float l_red[8][16];
  __shared__ float linv_lds[BQ2];

  int bid = blockIdx.x;
  int swz = (bid & 7) * (NBLK2/8) + (bid >> 3);      // XCD-aware, 3072 = 8*384
  int bh    = swz / QT2;
  int qt2   = swz % QT2;
  int b0    = bh / NH;
  int qbase = qt2 * BQ2;
  int rowoff = (qt2 & 1) * 16;                       // offset in 32-row bitmask

  int tid  = threadIdx.x;
  int w    = tid >> 6;       // 0..7
  int lane = tid & 63;
  int col  = lane & 15;
  int kg   = lane >> 4;

  const size_t bhSD = (size_t)bh * S * D;
  const unsigned* mqp = mq + ((size_t)b0*64 + (qt2 >> 1)) * S;

  // Q fragments (rows qbase + col), concat k-dim: a[0,1]=qr, a[2,3]=qi. /8.
  short8 a_r[4];
  {
    const float* qrp = q_real + bhSD + (size_t)(qbase + col) * D + kg*8;
    const float* qip = q_imag + bhSD + (size_t)(qbase + col) * D + kg*8;
    a_r[0] = pack8(*(const float4*)(qrp),      *(const float4*)(qrp + 4),  0.125f);
    a_r[1] = pack8(*(const float4*)(qrp + 32), *(const float4*)(qrp + 36), 0.125f);
    a_r[2] = pack8(*(const float4*)(qip),      *(const float4*)(qip + 4),  0.125f);
    a_r[3] = pack8(*(const float4*)(qip + 32), *(const float4*)(qip + 36), 0.125f);
  }

  float lsum[4] = {0.f, 0.f, 0.f, 0.f};

  // ---- Phase A: wave w scores keys [w*256, w*256+256) -> e-LDS; no barriers ----
  for (int t = 0; t < 8; t++){
    int grp = w*8 + t;                               // 32-key group
    const unsigned short* kb = kf + (size_t)(bh*64 + grp) * 4096;
    short8 bvA[4], bvB[4];
    #pragma unroll
    for (int kc = 0; kc < 4; kc++){
      bvA[kc] = *(const short8*)(kb + ((size_t)kc*64 + lane)*8);
      bvB[kc] = *(const short8*)(kb + ((size_t)(4+kc)*64 + lane)*8);
    }
    int keyA = grp*32 + 2*col;
    unsigned umA = mqp[keyA];
    unsigned umB = mqp[keyA + 1];

    f32x4 rA=(f32x4)(0.f), pA=(f32x4)(0.f), nA=(f32x4)(0.f);
    f32x4 rB=(f32x4)(0.f), pB=(f32x4)(0.f), nB=(f32x4)(0.f);
    #pragma unroll
    for (int kc = 0; kc < 4; kc++){
      rA = __builtin_amdgcn_mfma_f32_16x16x32_bf16(a_r[kc], bvA[kc], rA, 0, 0, 0);
      rB = __builtin_amdgcn_mfma_f32_16x16x32_bf16(a_r[kc], bvB[kc], rB, 0, 0, 0);
    }
    pA = __builtin_amdgcn_mfma_f32_16x16x32_bf16(a_r[2], bvA[0], pA, 0, 0, 0);
    pA = __builtin_amdgcn_mfma_f32_16x16x32_bf16(a_r[3], bvA[1], pA, 0, 0, 0);
    nA = __builtin_amdgcn_mfma_f32_16x16x32_bf16(a_r[0], bvA[2], nA, 0, 0, 0);
    nA = __builtin_amdgcn_mfma_f32_16x16x32_bf16(a_r[1], bvA[3], nA, 0, 0, 0);
    pB = __builtin_amdgcn_mfma_f32_16x16x32_bf16(a_r[2], bvB[0], pB, 0, 0, 0);
    pB = __builtin_amdgcn_mfma_f32_16x16x32_bf16(a_r[3], bvB[1], pB, 0, 0, 0);
    nB = __builtin_amdgcn_mfma_f32_16x16x32_bf16(a_r[0], bvB[2], nB, 0, 0, 0);
    nB = __builtin_amdgcn_mfma_f32_16x16x32_bf16(a_r[1], bvB[3], nB, 0, 0, 0);

    #pragma unroll
    for (int r = 0; r < 4; r++){
      int rowl = kg*4 + r;
      int rowb = rowoff + rowl;
      float iA = pA[r] - nA[r];
      float sA = sqrtf(rA[r]*rA[r] + iA*iA);
      float eA = ((umA >> rowb) & 1u) ? __expf(sA) : 0.f;
      float iB = pB[r] - nB[r];
      float sB = sqrtf(rB[r]*rB[r] + iB*iB);
      float eB = ((umB >> rowb) & 1u) ? __expf(sB) : 0.f;
      lsum[r] += eA + eB;
      unsigned pk = (unsigned)f2bf(eA) | ((unsigned)f2bf(eB) << 16);
      *(unsigned*)(elds + rowl*ESTRIDE + grp*64 + col*4) = pk;
    }
  }

  // ---- row-sum reduce -> linv ----
  #pragma unroll
  for (int r = 0; r < 4; r++){
    float v = lsum[r];
    v += __shfl_xor(v, 1); v += __shfl_xor(v, 2);
    v += __shfl_xor(v, 4); v += __shfl_xor(v, 8);
    if (col == 0) l_red[w][kg*4 + r] = v;
  }
  __syncthreads();
  if (tid < BQ2){
    float s = 0.f;
    #pragma unroll
    for (int ww = 0; ww < 8; ww++) s += l_red[ww][tid];
    linv_lds[tid] = 1.f / s;
  }
  __syncthreads();

  // ---- Phase B: PV from e-LDS; ri=0 waves also stream attn for win&3==dg ----
  {
    int ri = w >> 2;
    int dg = w & 3;
    const unsigned short* vbase = vf + ((size_t)(ri*NBH + bh)*4 + dg) * 64*64*8;
    float* attnp = out + 2*OUTSZ + (size_t)bh*S*S + (size_t)(qbase + col)*S + kg*8;
    float linv_c = linv_lds[col];                    // this lane's attn-row scale
    f32x4 acc = (f32x4)(0.f);
    for (int win = 0; win < 64; win++){
      short8 bv = *(const short8*)(vbase + ((size_t)win*64 + lane)*8);
      short8 a  = *(const short8*)(elds + col*ESTRIDE + win*64 + kg*16);
      acc = __builtin_amdgcn_mfma_f32_16x16x32_bf16(a, bv, acc, 0, 0, 0);
      if (ri == 0 && (win & 3) == dg){
        float4 o0, o1;
        o0.x = bf2f((unsigned short)a[0]) * linv_c;
        o0.y = bf2f((unsigned short)a[1]) * linv_c;
        o0.z = bf2f((unsigned short)a[2]) * linv_c;
        o0.w = bf2f((unsigned short)a[3]) * linv_c;
        o1.x = bf2f((unsigned short)a[4]) * linv_c;
        o1.y = bf2f((unsigned short)a[5]) * linv_c;
        o1.z = bf2f((unsigned short)a[6]) * linv_c;
        o1.w = bf2f((unsigned short)a[7]) * linv_c;
        float* p = attnp + win*32;
        *(float4*)(p)     = o0;
        *(float4*)(p + 4) = o1;
      }
    }
    float* outp = out + (ri ? OUTSZ : 0) + bhSD;
    #pragma unroll
    for (int r = 0; r < 4; r++){
      int row = kg*4 + r;
      outp[(size_t)(qbase + row) * D + dg*16 + col] = acc[r] * linv_lds[row];
    }
  }
}

// ---------------- tier-3: no-workspace fallback (round-2 kernel, proven) ----------
__global__ __launch_bounds__(512) void cattn_kernel(
    const float* __restrict__ q_real, const float* __restrict__ q_imag,
    const float* __restrict__ k_real, const float* __restrict__ k_imag,
    const float* __restrict__ v_real, const float* __restrict__ v_imag,
    const int*   __restrict__ mask,   float* __restrict__ out)
{
  extern __shared__ __align__(16) char lds[];
  float* l_lds = (float*)(lds + (size_t)BQ*S*2);
  float* l_inv = l_lds + 8*BQ;

  int bid = blockIdx.x;
  int swz = (bid & 7) * (NBLK/8) + (bid >> 3);
  int bh    = swz / QT;
  int qt    = swz % QT;
  int b0    = bh / NH;
  int qbase = qt * BQ;

  int tid  = threadIdx.x;
  int w    = tid >> 6;
  int lane = tid & 63;
  int col  = lane & 15;
  int kg   = lane >> 4;

  const size_t bhSD = (size_t)bh * S * D;

  short8 a_r[2][4], a_i[2][4];
  #pragma unroll
  for (int m = 0; m < 2; m++){
    const float* qrp = q_real + bhSD + (size_t)(qbase + m*16 + col) * D;
    const float* qip = q_imag + bhSD + (size_t)(qbase + m*16 + col) * D;
    #pragma unroll
    for (int h = 0; h < 2; h++){
      int d0 = h*32 + kg*8;
      float4 r0 = *(const float4*)(qrp + d0);
      float4 r1 = *(const float4*)(qrp + d0 + 4);
      float4 i0 = *(const float4*)(qip + d0);
      float4 i1 = *(const float4*)(qip + d0 + 4);
      a_r[m][h]   = pack8(r0, r1,  0.125f);
      a_r[m][2+h] = pack8(i0, i1,  0.125f);
      a_i[m][h]   = a_r[m][2+h];
      a_i[m][2+h] = pack8(r0, r1, -0.125f);
    }
  }

  float lsum[2][4] = {{0.f,0.f,0.f,0.f},{0.f,0.f,0.f,0.f}};
  const int* mrow = mask + (size_t)b0 * S * S;

  for (int t = 0; t < 16; t++){
    int key = w*256 + t*16 + col;
    const float* krp = k_real + bhSD + (size_t)key * D;
    const float* kip = k_imag + bhSD + (size_t)key * D;
    short8 bv[4];
    #pragma unroll
    for (int h = 0; h < 2; h++){
      int d0 = h*32 + kg*8;
      float4 r0 = *(const float4*)(krp + d0);
      float4 r1 = *(const float4*)(krp + d0 + 4);
      float4 i0 = *(const float4*)(kip + d0);
      float4 i1 = *(const float4*)(kip + d0 + 4);
      bv[h]   = pack8(r0, r1, 1.f);
      bv[2+h] = pack8(i0, i1, 1.f);
    }
    f32x4 accr[2], acci[2];
    #pragma unroll
    for (int m = 0; m < 2; m++){ accr[m] = (f32x4)(0.f); acci[m] = (f32x4)(0.f); }
    #pragma unroll
    for (int m = 0; m < 2; m++)
      #pragma unroll
      for (int kc = 0; kc < 4; kc++){
        accr[m] = __builtin_amdgcn_mfma_f32_16x16x32_bf16(a_r[m][kc], bv[kc], accr[m], 0, 0, 0);
        acci[m] = __builtin_amdgcn_mfma_f32_16x16x32_bf16(a_i[m][kc], bv[kc], acci[m], 0, 0, 0);
      }
    #pragma unroll
    for (int m = 0; m < 2; m++){
      int qrow_g = qbase + m*16 + kg*4;
      #pragma unroll
      for (int r = 0; r < 4; r++){
        float ar = accr[m][r], ai = acci[m][r];
        float s  = sqrtf(ar*ar + ai*ai);
        int  mv  = mrow[(size_t)(qrow_g + r) * S + key];
        float ex = __expf(s);
        float e  = mv ? ex : 0.f;
        lsum[m][r] += e;
        *(unsigned short*)(lds + eoff(m*16 + kg*4 + r, key)) = f2bf(e);
      }
    }
  }

  #pragma unroll
  for (int m = 0; m < 2; m++)
    #pragma unroll
    for (int r = 0; r < 4; r++){
      float v = lsum[m][r];
      v += __shfl_xor(v, 1); v += __shfl_xor(v, 2);
      v += __shfl_xor(v, 4); v += __shfl_xor(v, 8);
      lsum[m][r] = v;
    }
  if (col == 0){
    #pragma unroll
    for (int m = 0; m < 2; m++)
      #pragma unroll
      for (int r = 0; r < 4; r++)
        l_lds[w*BQ + m*16 + kg*4 + r] = lsum[m][r];
  }
  __syncthreads();
  if (tid < BQ){
    float t = 0.f;
    #pragma unroll
    for (int ww = 0; ww < 8; ww++) t += l_lds[ww*BQ + tid];
    l_inv[tid] = 1.f / t;
  }
  __syncthreads();

  {
    int ri    = w >> 2;
    int dbase = (w & 3) * 16;
    const float* vp = (ri ? v_imag : v_real) + bhSD;
    f32x4 acc[2]; acc[0] = (f32x4)(0.f); acc[1] = (f32x4)(0.f);
    for (int c = 0; c < 64; c++){
      int k0 = c*32 + kg*8;
      short8 bv;
      #pragma unroll
      for (int j = 0; j < 8; j++)
        bv[j] = (short)f2bf(vp[(size_t)(k0 + j) * D + dbase + col]);
      #pragma unroll
      for (int m = 0; m < 2; m++){
        short8 av = *(const short8*)(lds + eoff(m*16 + col, k0));
        acc[m] = __builtin_amdgcn_mfma_f32_16x16x32_bf16(av, bv, acc[m], 0, 0, 0);
      }
    }
    float* outp = out + (ri ? OUTSZ : 0) + bhSD;
    #pragma unroll
    for (int m = 0; m < 2; m++)
      #pragma unroll
      for (int r = 0; r < 4; r++){
        int row = m*16 + kg*4 + r;
        outp[(size_t)(qbase + row) * D + dbase + col] = acc[m][r] * l_inv[row];
      }
  }

  {
    float* attnp = out + 2*OUTSZ + (size_t)bh*S*S + (size_t)qbase*S;
    #pragma unroll
    for (int g = 0; g < 16; g++){
      int flat = g*4096 + tid*8;
      int row  = flat >> 11;
      int k    = flat & 2047;
      short8 ev = *(const short8*)(lds + eoff(row, k));
      float inv = l_inv[row];
      float4 o0, o1;
      o0.x = bf2f((unsigned short)ev[0]) * inv;
      o0.y = bf2f((unsigned short)ev[1]) * inv;
      o0.z = bf2f((unsigned short)ev[2]) * inv;
      o0.w = bf2f((unsigned short)ev[3]) * inv;
      o1.x = bf2f((unsigned short)ev[4]) * inv;
      o1.y = bf2f((unsigned short)ev[5]) * inv;
      o1.z = bf2f((unsigned short)ev[6]) * inv;
      o1.w = bf2f((unsigned short)ev[7]) * inv;
      *(float4*)(attnp + (size_t)row*S + k)     = o0;
      *(float4*)(attnp + (size_t)row*S + k + 4) = o1;
    }
  }
}

extern "C" void kernel_launch(void* const* d_in, const int* in_sizes, int n_in,
                              void* d_out, int out_size, void* d_ws, size_t ws_size,
                              hipStream_t stream)
{
  const float* qr = (const float*)d_in[0];
  const float* qi = (const float*)d_in[1];
  const float* kr = (const float*)d_in[2];
  const float* ki = (const float*)d_in[3];
  const float* vr = (const float*)d_in[4];
  const float* vi = (const float*)d_in[5];
  const int*   mk = (const int*)d_in[6];
  float* out = (float*)d_out;

  if (ws_size >= WS_NEED){
    unsigned short* kf = (unsigned short*)((char*)d_ws + KF_OFF);
    unsigned short* vf = (unsigned short*)((char*)d_ws + VF_OFF);
    unsigned*       mq = (unsigned*)((char*)d_ws + MQ_OFF);
    conv_all<<<dim3(CONV_BLKS), dim3(256), 0, stream>>>(kr, ki, vr, vi, mk, kf, vf, mq);
    cattn_merged<<<dim3(NBLK2), dim3(512), 0, stream>>>(qr, qi, kf, vf, mq, out);
  } else {
    size_t ldsb = (size_t)BQ*S*2 + (size_t)8*BQ*4 + (size_t)BQ*4;
    cattn_kernel<<<dim3(NBLK), dim3(512), ldsb, stream>>>(qr, qi, kr, ki, vr, vi, mk, out);
  }
}

// Round 15
// 335.123 us; speedup vs baseline: 1.1436x; 1.1436x over previous
//
#include <hip/hip_runtime.h>

#define S     2048
#define D     64
#define NH    12
#define NB    2
#define NBH   (NB*NH)       // 24
#define OUTSZ ((size_t)NBH*S*D)

#define BQ    32
#define QT    (S/BQ)        // 64
#define NBLK  (NBH*QT)      // 1536  (fallback grid)

#define BQ2   16
#define QT2   (S/BQ2)       // 128
#define NBLK2 (NBH*QT2)     // 3072

// workspace layout (bytes): converted operands only
#define KF_OFF    0
#define KF_SZ     ((size_t)NBH*S*128*2)        // 12582912 (fragment-ordered K)
#define VF_OFF    (KF_OFF + KF_SZ)
#define VF_SZ     ((size_t)2*NBH*D*S*2)        // 12582912 (fragment-ordered V)
#define MQ_OFF    (VF_OFF + VF_SZ)
#define MQ_SZ     ((size_t)NB*QT*S*4)          // 1048576 (32-row bitmasks)
#define WS_NEED   (MQ_OFF + MQ_SZ)             // 26214400

// fused conv grid partition
#define CK_BLKS   3072
#define CV_BLKS   (2*NBH*32)                   // 1536
#define CM_BLKS   (NB*QT)                      // 128
#define CONV_BLKS (CK_BLKS + CV_BLKS + CM_BLKS)

typedef __attribute__((ext_vector_type(8))) short short8;
typedef __attribute__((ext_vector_type(4))) float f32x4;

__device__ __forceinline__ unsigned short f2bf(float x){
  unsigned u = __builtin_bit_cast(unsigned, x);
  u += 0x7fffu + ((u >> 16) & 1u);       // RTNE
  return (unsigned short)(u >> 16);
}
__device__ __forceinline__ float bf2f(unsigned short h){
  unsigned u = ((unsigned)h) << 16;
  return __builtin_bit_cast(float, u);
}
__device__ __forceinline__ short8 pack8(const float4& a, const float4& b, float sc){
  short8 r;
  r[0]=(short)f2bf(a.x*sc); r[1]=(short)f2bf(a.y*sc);
  r[2]=(short)f2bf(a.z*sc); r[3]=(short)f2bf(a.w*sc);
  r[4]=(short)f2bf(b.x*sc); r[5]=(short)f2bf(b.y*sc);
  r[6]=(short)f2bf(b.z*sc); r[7]=(short)f2bf(b.w*sc);
  return r;
}
__device__ __forceinline__ int eoff(int row, int key){
  return ((row << 12) | (key << 1)) ^ ((row & 7) << 4);
}

// ------- fused conversions: K->kf frag order, V->vf frag order, mask->bitmask ----
__global__ __launch_bounds__(256) void conv_all(
    const float* __restrict__ kr, const float* __restrict__ ki,
    const float* __restrict__ vr, const float* __restrict__ vi,
    const int*   __restrict__ mask,
    unsigned short* __restrict__ kf, unsigned short* __restrict__ vf,
    unsigned* __restrict__ mq)
{
  __shared__ __align__(4) unsigned short tile[64][65];   // conv_v transpose tile
  int blk = blockIdx.x;
  int t   = threadIdx.x;

  if (blk < CK_BLKS){
    // K -> kf[bh][grp64][eo2][kc4][lane64][8]
    int idx  = blk*256 + t;
    int lane = idx & 63;
    int kc   = (idx >> 6) & 3;
    int eo   = (idx >> 8) & 1;
    int grp  = (idx >> 9) & 63;
    int bh   = idx >> 15;
    int key  = grp*32 + 2*(lane & 15) + eo;
    int d0   = kc*32 + (lane >> 4)*8;
    const float* src = (d0 < 64) ? kr + ((size_t)bh*S + key)*64 + d0
                                 : ki + ((size_t)bh*S + key)*64 + (d0 - 64);
    float4 a = *(const float4*)(src);
    float4 b = *(const float4*)(src + 4);
    *(short8*)(kf + (size_t)idx*8) = pack8(a, b, 1.f);
  } else if (blk < CK_BLKS + CV_BLKS){
    // V -> vf[ri*NBH+bh][dg4][c64][lane64][8]
    int bid = blk - CK_BLKS;
    int ri  = bid / (NBH*32);
    int rem = bid % (NBH*32);
    int bh  = rem / 32;
    int s0  = (rem % 32) * 64;
    const float* vp = (ri ? vi : vr) + (size_t)bh*S*D;
    #pragma unroll
    for (int it = 0; it < 4; it++){
      int row = (t >> 4) + it*16;                // s_local
      int c4  = (t & 15) * 4;                    // d
      float4 v = *(const float4*)(vp + (size_t)(s0+row)*D + c4);
      tile[c4+0][row] = f2bf(v.x);
      tile[c4+1][row] = f2bf(v.y);
      tile[c4+2][row] = f2bf(v.z);
      tile[c4+3][row] = f2bf(v.w);
    }
    __syncthreads();
    unsigned short* dst = vf + (size_t)(ri*NBH + bh) * 4*64*64*8;
    #pragma unroll
    for (int u = 0; u < 2; u++){
      int comb = u*256 + t;
      int lane = comb & 63;
      int cp   = (comb >> 6) & 1;
      int dg   = comb >> 7;
      int c    = s0/32 + cp;
      int d    = dg*16 + (lane & 15);
      int sl   = cp*32 + (lane >> 4)*8;
      short8 o;
      #pragma unroll
      for (int j = 0; j < 8; j++) o[j] = (short)tile[d][sl + j];
      *(short8*)(dst + (((size_t)dg*64 + c)*64 + lane)*8) = o;
    }
  } else {
    // mask -> mq[b][qt32][key] bitmask of 32 q-rows
    int bid = blk - CK_BLKS - CV_BLKS;
    int b   = bid >> 6;
    int qt  = bid & 63;
    int qbase = qt * BQ;
    #pragma unroll
    for (int it = 0; it < 8; it++){
      int key = it*256 + t;
      unsigned bits = 0;
      #pragma unroll
      for (int j = 0; j < 32; j++)
        bits |= (mask[((size_t)b*S + qbase + j)*S + key] ? 1u : 0u) << j;
      mq[((size_t)b*64 + qt)*S + key] = bits;
    }
  }
}

// ---- merged kernel v4 (round-13 proven, 245 us): full-row e tile in LDS ----
// Phase A: score once -> e-LDS (no barriers). Phase B: PV from LDS.
// Phase C: attn = e * linv (linear LDS reads + coalesced stores).
#define ESTRIDE 4144   // 2048 keys * 2B + 48B pad -> row stride 12 banks mod 32

__global__ __launch_bounds__(512) void cattn_merged(
    const float* __restrict__ q_real, const float* __restrict__ q_imag,
    const unsigned short* __restrict__ kf,
    const unsigned short* __restrict__ vf,
    const unsigned* __restrict__ mq,
    float* __restrict__ out)
{
  __shared__ __align__(16) char elds[BQ2*ESTRIDE];   // 66304 B
  __shared__ float l_red[8][16];
  __shared__ float linv_lds[BQ2];

  int bid = blockIdx.x;
  int swz = (bid & 7) * (NBLK2/8) + (bid >> 3);      // XCD-aware, 3072 = 8*384
  int bh    = swz / QT2;
  int qt2   = swz % QT2;
  int b0    = bh / NH;
  int qbase = qt2 * BQ2;
  int rowoff = (qt2 & 1) * 16;                       // offset in 32-row bitmask

  int tid  = threadIdx.x;
  int w    = tid >> 6;       // 0..7
  int lane = tid & 63;
  int col  = lane & 15;
  int kg   = lane >> 4;

  const size_t bhSD = (size_t)bh * S * D;
  const unsigned* mqp = mq + ((size_t)b0*64 + (qt2 >> 1)) * S;

  // Q fragments (rows qbase + col), concat k-dim: a[0,1]=qr, a[2,3]=qi. /8.
  short8 a_r[4];
  {
    const float* qrp = q_real + bhSD + (size_t)(qbase + col) * D + kg*8;
    const float* qip = q_imag + bhSD + (size_t)(qbase + col) * D + kg*8;
    a_r[0] = pack8(*(const float4*)(qrp),      *(const float4*)(qrp + 4),  0.125f);
    a_r[1] = pack8(*(const float4*)(qrp + 32), *(const float4*)(qrp + 36), 0.125f);
    a_r[2] = pack8(*(const float4*)(qip),      *(const float4*)(qip + 4),  0.125f);
    a_r[3] = pack8(*(const float4*)(qip + 32), *(const float4*)(qip + 36), 0.125f);
  }

  float lsum[4] = {0.f, 0.f, 0.f, 0.f};

  // ---- Phase A: wave w scores keys [w*256, w*256+256) -> e-LDS; no barriers ----
  for (int t = 0; t < 8; t++){
    int grp = w*8 + t;                               // 32-key group
    const unsigned short* kb = kf + (size_t)(bh*64 + grp) * 4096;
    short8 bvA[4], bvB[4];
    #pragma unroll
    for (int kc = 0; kc < 4; kc++){
      bvA[kc] = *(const short8*)(kb + ((size_t)kc*64 + lane)*8);
      bvB[kc] = *(const short8*)(kb + ((size_t)(4+kc)*64 + lane)*8);
    }
    int keyA = grp*32 + 2*col;
    unsigned umA = mqp[keyA];
    unsigned umB = mqp[keyA + 1];

    f32x4 rA=(f32x4)(0.f), pA=(f32x4)(0.f), nA=(f32x4)(0.f);
    f32x4 rB=(f32x4)(0.f), pB=(f32x4)(0.f), nB=(f32x4)(0.f);
    #pragma unroll
    for (int kc = 0; kc < 4; kc++){
      rA = __builtin_amdgcn_mfma_f32_16x16x32_bf16(a_r[kc], bvA[kc], rA, 0, 0, 0);
      rB = __builtin_amdgcn_mfma_f32_16x16x32_bf16(a_r[kc], bvB[kc], rB, 0, 0, 0);
    }
    pA = __builtin_amdgcn_mfma_f32_16x16x32_bf16(a_r[2], bvA[0], pA, 0, 0, 0);
    pA = __builtin_amdgcn_mfma_f32_16x16x32_bf16(a_r[3], bvA[1], pA, 0, 0, 0);
    nA = __builtin_amdgcn_mfma_f32_16x16x32_bf16(a_r[0], bvA[2], nA, 0, 0, 0);
    nA = __builtin_amdgcn_mfma_f32_16x16x32_bf16(a_r[1], bvA[3], nA, 0, 0, 0);
    pB = __builtin_amdgcn_mfma_f32_16x16x32_bf16(a_r[2], bvB[0], pB, 0, 0, 0);
    pB = __builtin_amdgcn_mfma_f32_16x16x32_bf16(a_r[3], bvB[1], pB, 0, 0, 0);
    nB = __builtin_amdgcn_mfma_f32_16x16x32_bf16(a_r[0], bvB[2], nB, 0, 0, 0);
    nB = __builtin_amdgcn_mfma_f32_16x16x32_bf16(a_r[1], bvB[3], nB, 0, 0, 0);

    #pragma unroll
    for (int r = 0; r < 4; r++){
      int rowl = kg*4 + r;
      int rowb = rowoff + rowl;
      float iA = pA[r] - nA[r];
      float sA = sqrtf(rA[r]*rA[r] + iA*iA);
      float eA = ((umA >> rowb) & 1u) ? __expf(sA) : 0.f;
      float iB = pB[r] - nB[r];
      float sB = sqrtf(rB[r]*rB[r] + iB*iB);
      float eB = ((umB >> rowb) & 1u) ? __expf(sB) : 0.f;
      lsum[r] += eA + eB;
      unsigned pk = (unsigned)f2bf(eA) | ((unsigned)f2bf(eB) << 16);
      *(unsigned*)(elds + rowl*ESTRIDE + grp*64 + col*4) = pk;
    }
  }

  // ---- row-sum reduce -> linv ----
  #pragma unroll
  for (int r = 0; r < 4; r++){
    float v = lsum[r];
    v += __shfl_xor(v, 1); v += __shfl_xor(v, 2);
    v += __shfl_xor(v, 4); v += __shfl_xor(v, 8);
    if (col == 0) l_red[w][kg*4 + r] = v;
  }
  __syncthreads();
  if (tid < BQ2){
    float s = 0.f;
    #pragma unroll
    for (int ww = 0; ww < 8; ww++) s += l_red[ww][tid];
    linv_lds[tid] = 1.f / s;
  }
  __syncthreads();

  // ---- Phase B: PV from e-LDS; wave w -> ri = w>>2, dg = w&3 ----
  {
    int ri = w >> 2;
    int dg = w & 3;
    const unsigned short* vbase = vf + ((size_t)(ri*NBH + bh)*4 + dg) * 64*64*8;
    f32x4 acc = (f32x4)(0.f);
    for (int win = 0; win < 64; win++){
      short8 bv = *(const short8*)(vbase + ((size_t)win*64 + lane)*8);
      short8 a  = *(const short8*)(elds + col*ESTRIDE + win*64 + kg*16);
      acc = __builtin_amdgcn_mfma_f32_16x16x32_bf16(a, bv, acc, 0, 0, 0);
    }
    float* outp = out + (ri ? OUTSZ : 0) + bhSD;
    #pragma unroll
    for (int r = 0; r < 4; r++){
      int row = kg*4 + r;
      outp[(size_t)(qbase + row) * D + dg*16 + col] = acc[r] * linv_lds[row];
    }
  }

  // ---- Phase C: attn = e * linv; linear LDS reads, coalesced float2 stores ----
  {
    float* attnp = out + 2*OUTSZ + (size_t)bh*S*S + (size_t)qbase*S;
    #pragma unroll 4
    for (int it = 0; it < 32; it++){
      int p   = it*512 + tid;                        // pair index, 16*1024 total
      int row = p >> 10;
      int po  = p & 1023;
      unsigned pk = *(const unsigned*)(elds + row*ESTRIDE + po*4);
      float inv = linv_lds[row];
      float2 o;
      o.x = bf2f((unsigned short)(pk & 0xffffu)) * inv;
      o.y = bf2f((unsigned short)(pk >> 16))     * inv;
      *(float2*)(attnp + (size_t)row*S + 2*po) = o;
    }
  }
}

// ---------------- tier-3: no-workspace fallback (round-2 kernel, proven) ----------
__global__ __launch_bounds__(512) void cattn_kernel(
    const float* __restrict__ q_real, const float* __restrict__ q_imag,
    const float* __restrict__ k_real, const float* __restrict__ k_imag,
    const float* __restrict__ v_real, const float* __restrict__ v_imag,
    const int*   __restrict__ mask,   float* __restrict__ out)
{
  extern __shared__ __align__(16) char lds[];
  float* l_lds = (float*)(lds + (size_t)BQ*S*2);
  float* l_inv = l_lds + 8*BQ;

  int bid = blockIdx.x;
  int swz = (bid & 7) * (NBLK/8) + (bid >> 3);
  int bh    = swz / QT;
  int qt    = swz % QT;
  int b0    = bh / NH;
  int qbase = qt * BQ;

  int tid  = threadIdx.x;
  int w    = tid >> 6;
  int lane = tid & 63;
  int col  = lane & 15;
  int kg   = lane >> 4;

  const size_t bhSD = (size_t)bh * S * D;

  short8 a_r[2][4], a_i[2][4];
  #pragma unroll
  for (int m = 0; m < 2; m++){
    const float* qrp = q_real + bhSD + (size_t)(qbase + m*16 + col) * D;
    const float* qip = q_imag + bhSD + (size_t)(qbase + m*16 + col) * D;
    #pragma unroll
    for (int h = 0; h < 2; h++){
      int d0 = h*32 + kg*8;
      float4 r0 = *(const float4*)(qrp + d0);
      float4 r1 = *(const float4*)(qrp + d0 + 4);
      float4 i0 = *(const float4*)(qip + d0);
      float4 i1 = *(const float4*)(qip + d0 + 4);
      a_r[m][h]   = pack8(r0, r1,  0.125f);
      a_r[m][2+h] = pack8(i0, i1,  0.125f);
      a_i[m][h]   = a_r[m][2+h];
      a_i[m][2+h] = pack8(r0, r1, -0.125f);
    }
  }

  float lsum[2][4] = {{0.f,0.f,0.f,0.f},{0.f,0.f,0.f,0.f}};
  const int* mrow = mask + (size_t)b0 * S * S;

  for (int t = 0; t < 16; t++){
    int key = w*256 + t*16 + col;
    const float* krp = k_real + bhSD + (size_t)key * D;
    const float* kip = k_imag + bhSD + (size_t)key * D;
    short8 bv[4];
    #pragma unroll
    for (int h = 0; h < 2; h++){
      int d0 = h*32 + kg*8;
      float4 r0 = *(const float4*)(krp + d0);
      float4 r1 = *(const float4*)(krp + d0 + 4);
      float4 i0 = *(const float4*)(kip + d0);
      float4 i1 = *(const float4*)(kip + d0 + 4);
      bv[h]   = pack8(r0, r1, 1.f);
      bv[2+h] = pack8(i0, i1, 1.f);
    }
    f32x4 accr[2], acci[2];
    #pragma unroll
    for (int m = 0; m < 2; m++){ accr[m] = (f32x4)(0.f); acci[m] = (f32x4)(0.f); }
    #pragma unroll
    for (int m = 0; m < 2; m++)
      #pragma unroll
      for (int kc = 0; kc < 4; kc++){
        accr[m] = __builtin_amdgcn_mfma_f32_16x16x32_bf16(a_r[m][kc], bv[kc], accr[m], 0, 0, 0);
        acci[m] = __builtin_amdgcn_mfma_f32_16x16x32_bf16(a_i[m][kc], bv[kc], acci[m], 0, 0, 0);
      }
    #pragma unroll
    for (int m = 0; m < 2; m++){
      int qrow_g = qbase + m*16 + kg*4;
      #pragma unroll
      for (int r = 0; r < 4; r++){
        float ar = accr[m][r], ai = acci[m][r];
        float s  = sqrtf(ar*ar + ai*ai);
        int  mv  = mrow[(size_t)(qrow_g + r) * S + key];
        float ex = __expf(s);
        float e  = mv ? ex : 0.f;
        lsum[m][r] += e;
        *(unsigned short*)(lds + eoff(m*16 + kg*4 + r, key)) = f2bf(e);
      }
    }
  }

  #pragma unroll
  for (int m = 0; m < 2; m++)
    #pragma unroll
    for (int r = 0; r < 4; r++){
      float v = lsum[m][r];
      v += __shfl_xor(v, 1); v += __shfl_xor(v, 2);
      v += __shfl_xor(v, 4); v += __shfl_xor(v, 8);
      lsum[m][r] = v;
    }
  if (col == 0){
    #pragma unroll
    for (int m = 0; m < 2; m++)
      #pragma unroll
      for (int r = 0; r < 4; r++)
        l_lds[w*BQ + m*16 + kg*4 + r] = lsum[m][r];
  }
  __syncthreads();
  if (tid < BQ){
    float t = 0.f;
    #pragma unroll
    for (int ww = 0; ww < 8; ww++) t += l_lds[ww*BQ + tid];
    l_inv[tid] = 1.f / t;
  }
  __syncthreads();

  {
    int ri    = w >> 2;
    int dbase = (w & 3) * 16;
    const float* vp = (ri ? v_imag : v_real) + bhSD;
    f32x4 acc[2]; acc[0] = (f32x4)(0.f); acc[1] = (f32x4)(0.f);
    for (int c = 0; c < 64; c++){
      int k0 = c*32 + kg*8;
      short8 bv;
      #pragma unroll
      for (int j = 0; j < 8; j++)
        bv[j] = (short)f2bf(vp[(size_t)(k0 + j) * D + dbase + col]);
      #pragma unroll
      for (int m = 0; m < 2; m++){
        short8 av = *(const short8*)(lds + eoff(m*16 + col, k0));
        acc[m] = __builtin_amdgcn_mfma_f32_16x16x32_bf16(av, bv, acc[m], 0, 0, 0);
      }
    }
    float* outp = out + (ri ? OUTSZ : 0) + bhSD;
    #pragma unroll
    for (int m = 0; m < 2; m++)
      #pragma unroll
      for (int r = 0; r < 4; r++){
        int row = m*16 + kg*4 + r;
        outp[(size_t)(qbase + row) * D + dbase + col] = acc[m][r] * l_inv[row];
      }
  }

  {
    float* attnp = out + 2*OUTSZ + (size_t)bh*S*S + (size_t)qbase*S;
    #pragma unroll
    for (int g = 0; g < 16; g++){
      int flat = g*4096 + tid*8;
      int row  = flat >> 11;
      int k    = flat & 2047;
      short8 ev = *(const short8*)(lds + eoff(row, k));
      float inv = l_inv[row];
      float4 o0, o1;
      o0.x = bf2f((unsigned short)ev[0]) * inv;
      o0.y = bf2f((unsigned short)ev[1]) * inv;
      o0.z = bf2f((unsigned short)ev[2]) * inv;
      o0.w = bf2f((unsigned short)ev[3]) * inv;
      o1.x = bf2f((unsigned short)ev[4]) * inv;
      o1.y = bf2f((unsigned short)ev[5]) * inv;
      o1.z = bf2f((unsigned short)ev[6]) * inv;
      o1.w = bf2f((unsigned short)ev[7]) * inv;
      *(float4*)(attnp + (size_t)row*S + k)     = o0;
      *(float4*)(attnp + (size_t)row*S + k + 4) = o1;
    }
  }
}

extern "C" void kernel_launch(void* const* d_in, const int* in_sizes, int n_in,
                              void* d_out, int out_size, void* d_ws, size_t ws_size,
                              hipStream_t stream)
{
  const float* qr = (const float*)d_in[0];
  const float* qi = (const float*)d_in[1];
  const float* kr = (const float*)d_in[2];
  const float* ki = (const float*)d_in[3];
  const float* vr = (const float*)d_in[4];
  const float* vi = (const float*)d_in[5];
  const int*   mk = (const int*)d_in[6];
  float* out = (float*)d_out;

  if (ws_size >= WS_NEED){
    unsigned short* kf = (unsigned short*)((char*)d_ws + KF_OFF);
    unsigned short* vf = (unsigned short*)((char*)d_ws + VF_OFF);
    unsigned*       mq = (unsigned*)((char*)d_ws + MQ_OFF);
    conv_all<<<dim3(CONV_BLKS), dim3(256), 0, stream>>>(kr, ki, vr, vi, mk, kf, vf, mq);
    cattn_merged<<<dim3(NBLK2), dim3(512), 0, stream>>>(qr, qi, kf, vf, mq, out);
  } else {
    size_t ldsb = (size_t)BQ*S*2 + (size_t)8*BQ*4 + (size_t)BQ*4;
    cattn_kernel<<<dim3(NBLK), dim3(512), ldsb, stream>>>(qr, qi, kr, ki, vr, vi, mk, out);
  }
}

// Round 16
// 244.292 us; speedup vs baseline: 1.5688x; 1.3718x over previous
//
#include <hip/hip_runtime.h>

#define S     2048
#define D     64
#define NH    12
#define NB    2
#define NBH   (NB*NH)       // 24
#define OUTSZ ((size_t)NBH*S*D)

#define BQ    32
#define QT    (S/BQ)        // 64
#define NBLK  (NBH*QT)      // 1536  (fallback grid)

#define BQ2   16
#define QT2   (S/BQ2)       // 128
#define NBLK2 (NBH*QT2)     // 3072

// workspace layout (bytes): converted operands only
#define KF_OFF    0
#define KF_SZ     ((size_t)NBH*S*128*2)        // 12582912 (fragment-ordered K)
#define VF_OFF    (KF_OFF + KF_SZ)
#define VF_SZ     ((size_t)2*NBH*D*S*2)        // 12582912 (fragment-ordered V)
#define MQ_OFF    (VF_OFF + VF_SZ)
#define MQ_SZ     ((size_t)NB*QT*S*4)          // 1048576 (32-row bitmasks)
#define WS_NEED   (MQ_OFF + MQ_SZ)             // 26214400

typedef __attribute__((ext_vector_type(8))) short short8;
typedef __attribute__((ext_vector_type(4))) float f32x4;

__device__ __forceinline__ unsigned short f2bf(float x){
  unsigned u = __builtin_bit_cast(unsigned, x);
  u += 0x7fffu + ((u >> 16) & 1u);       // RTNE
  return (unsigned short)(u >> 16);
}
__device__ __forceinline__ float bf2f(unsigned short h){
  unsigned u = ((unsigned)h) << 16;
  return __builtin_bit_cast(float, u);
}
__device__ __forceinline__ short8 pack8(const float4& a, const float4& b, float sc){
  short8 r;
  r[0]=(short)f2bf(a.x*sc); r[1]=(short)f2bf(a.y*sc);
  r[2]=(short)f2bf(a.z*sc); r[3]=(short)f2bf(a.w*sc);
  r[4]=(short)f2bf(b.x*sc); r[5]=(short)f2bf(b.y*sc);
  r[6]=(short)f2bf(b.z*sc); r[7]=(short)f2bf(b.w*sc);
  return r;
}
__device__ __forceinline__ int eoff(int row, int key){
  return ((row << 12) | (key << 1)) ^ ((row & 7) << 4);
}

// ------- conv_k: K -> fragment order kf[bh][grp64][eo2][kc4][lane64][8] -------
__global__ __launch_bounds__(256) void conv_k(const float* __restrict__ kr,
                                              const float* __restrict__ ki,
                                              unsigned short* __restrict__ kf){
  int idx  = blockIdx.x*256 + threadIdx.x;     // 786432 total
  int lane = idx & 63;
  int kc   = (idx >> 6) & 3;
  int eo   = (idx >> 8) & 1;
  int grp  = (idx >> 9) & 63;
  int bh   = idx >> 15;
  int key  = grp*32 + 2*(lane & 15) + eo;
  int d0   = kc*32 + (lane >> 4)*8;
  const float* src = (d0 < 64) ? kr + ((size_t)bh*S + key)*64 + d0
                               : ki + ((size_t)bh*S + key)*64 + (d0 - 64);
  float4 a = *(const float4*)(src);
  float4 b = *(const float4*)(src + 4);
  *(short8*)(kf + (size_t)idx*8) = pack8(a, b, 1.f);
}

// ------- conv_v: V -> fragment order vf[ri*NBH+bh][dg4][c64][lane64][8] -------
__global__ __launch_bounds__(256) void conv_v(const float* __restrict__ vr,
                                              const float* __restrict__ vi,
                                              unsigned short* __restrict__ vf){
  __shared__ unsigned short tile[64][65];      // [d][s_local]
  int bid = blockIdx.x;
  int ri  = bid / (NBH*32);
  int rem = bid % (NBH*32);
  int bh  = rem / 32;
  int s0  = (rem % 32) * 64;
  const float* vp = (ri ? vi : vr) + (size_t)bh*S*D;
  int t = threadIdx.x;
  #pragma unroll
  for (int it = 0; it < 4; it++){
    int row = (t >> 4) + it*16;                // s_local
    int c4  = (t & 15) * 4;                    // d
    float4 v = *(const float4*)(vp + (size_t)(s0+row)*D + c4);
    tile[c4+0][row] = f2bf(v.x);
    tile[c4+1][row] = f2bf(v.y);
    tile[c4+2][row] = f2bf(v.z);
    tile[c4+3][row] = f2bf(v.w);
  }
  __syncthreads();
  unsigned short* dst = vf + (size_t)(ri*NBH + bh) * 4*64*64*8;
  #pragma unroll
  for (int u = 0; u < 2; u++){
    int comb = u*256 + t;                      // 512 combos = dg*2cp*64lane
    int lane = comb & 63;
    int cp   = (comb >> 6) & 1;
    int dg   = comb >> 7;
    int c    = s0/32 + cp;
    int d    = dg*16 + (lane & 15);
    int sl   = cp*32 + (lane >> 4)*8;          // s_local
    short8 o;
    #pragma unroll
    for (int j = 0; j < 8; j++) o[j] = (short)tile[d][sl + j];
    *(short8*)(dst + (((size_t)dg*64 + c)*64 + lane)*8) = o;
  }
}

// ------- conv_m: mask -> mq32[b][qt32][key] bitmask of 32 q-rows -------
__global__ __launch_bounds__(256) void conv_m(const int* __restrict__ mask,
                                              unsigned* __restrict__ mq){
  int b  = blockIdx.x >> 6;
  int qt = blockIdx.x & 63;
  int qbase = qt * BQ;
  int t = threadIdx.x;
  #pragma unroll
  for (int it = 0; it < 8; it++){
    int key = it*256 + t;
    unsigned bits = 0;
    #pragma unroll
    for (int j = 0; j < 32; j++)
      bits |= (mask[((size_t)b*S + qbase + j)*S + key] ? 1u : 0u) << j;
    mq[((size_t)b*64 + qt)*S + key] = bits;
  }
}

// ---- merged kernel v4: BQ=16, 512 thr / 8 waves, full-row e tile in LDS ----
// Phase A: score once -> e-LDS (no barriers). Phase B: PV from LDS.
// Phase C: attn = e * linv (linear LDS reads). Scores computed exactly once.
#define ESTRIDE 4144   // 2048 keys * 2B + 48B pad -> row stride 12 banks mod 32

__global__ __launch_bounds__(512) void cattn_merged(
    const float* __restrict__ q_real, const float* __restrict__ q_imag,
    const unsigned short* __restrict__ kf,
    const unsigned short* __restrict__ vf,
    const unsigned* __restrict__ mq,
    float* __restrict__ out)
{
  __shared__ __align__(16) char elds[BQ2*ESTRIDE];   // 66304 B
  __shared__ float l_red[8][16];
  __shared__ float linv_lds[BQ2];

  int bid = blockIdx.x;
  int swz = (bid & 7) * (NBLK2/8) + (bid >> 3);      // XCD-aware, 3072 = 8*384
  int bh    = swz / QT2;
  int qt2   = swz % QT2;
  int b0    = bh / NH;
  int qbase = qt2 * BQ2;
  int rowoff = (qt2 & 1) * 16;                       // offset in 32-row bitmask

  int tid  = threadIdx.x;
  int w    = tid >> 6;       // 0..7
  int lane = tid & 63;
  int col  = lane & 15;
  int kg   = lane >> 4;

  const size_t bhSD = (size_t)bh * S * D;
  const unsigned* mqp = mq + ((size_t)b0*64 + (qt2 >> 1)) * S;

  // Q fragments (rows qbase + col), concat k-dim: a[0,1]=qr, a[2,3]=qi. /8.
  short8 a_r[4];
  {
    const float* qrp = q_real + bhSD + (size_t)(qbase + col) * D + kg*8;
    const float* qip = q_imag + bhSD + (size_t)(qbase + col) * D + kg*8;
    a_r[0] = pack8(*(const float4*)(qrp),      *(const float4*)(qrp + 4),  0.125f);
    a_r[1] = pack8(*(const float4*)(qrp + 32), *(const float4*)(qrp + 36), 0.125f);
    a_r[2] = pack8(*(const float4*)(qip),      *(const float4*)(qip + 4),  0.125f);
    a_r[3] = pack8(*(const float4*)(qip + 32), *(const float4*)(qip + 36), 0.125f);
  }

  float lsum[4] = {0.f, 0.f, 0.f, 0.f};

  // ---- Phase A: wave w scores keys [w*256, w*256+256) -> e-LDS; no barriers ----
  for (int t = 0; t < 8; t++){
    int grp = w*8 + t;                               // 32-key group
    const unsigned short* kb = kf + (size_t)(bh*64 + grp) * 4096;
    short8 bvA[4], bvB[4];
    #pragma unroll
    for (int kc = 0; kc < 4; kc++){
      bvA[kc] = *(const short8*)(kb + ((size_t)kc*64 + lane)*8);
      bvB[kc] = *(const short8*)(kb + ((size_t)(4+kc)*64 + lane)*8);
    }
    int keyA = grp*32 + 2*col;
    unsigned umA = mqp[keyA];
    unsigned umB = mqp[keyA + 1];

    f32x4 rA=(f32x4)(0.f), pA=(f32x4)(0.f), nA=(f32x4)(0.f);
    f32x4 rB=(f32x4)(0.f), pB=(f32x4)(0.f), nB=(f32x4)(0.f);
    #pragma unroll
    for (int kc = 0; kc < 4; kc++){
      rA = __builtin_amdgcn_mfma_f32_16x16x32_bf16(a_r[kc], bvA[kc], rA, 0, 0, 0);
      rB = __builtin_amdgcn_mfma_f32_16x16x32_bf16(a_r[kc], bvB[kc], rB, 0, 0, 0);
    }
    pA = __builtin_amdgcn_mfma_f32_16x16x32_bf16(a_r[2], bvA[0], pA, 0, 0, 0);
    pA = __builtin_amdgcn_mfma_f32_16x16x32_bf16(a_r[3], bvA[1], pA, 0, 0, 0);
    nA = __builtin_amdgcn_mfma_f32_16x16x32_bf16(a_r[0], bvA[2], nA, 0, 0, 0);
    nA = __builtin_amdgcn_mfma_f32_16x16x32_bf16(a_r[1], bvA[3], nA, 0, 0, 0);
    pB = __builtin_amdgcn_mfma_f32_16x16x32_bf16(a_r[2], bvB[0], pB, 0, 0, 0);
    pB = __builtin_amdgcn_mfma_f32_16x16x32_bf16(a_r[3], bvB[1], pB, 0, 0, 0);
    nB = __builtin_amdgcn_mfma_f32_16x16x32_bf16(a_r[0], bvB[2], nB, 0, 0, 0);
    nB = __builtin_amdgcn_mfma_f32_16x16x32_bf16(a_r[1], bvB[3], nB, 0, 0, 0);

    #pragma unroll
    for (int r = 0; r < 4; r++){
      int rowl = kg*4 + r;
      int rowb = rowoff + rowl;
      float iA = pA[r] - nA[r];
      float sA = sqrtf(rA[r]*rA[r] + iA*iA);
      float eA = ((umA >> rowb) & 1u) ? __expf(sA) : 0.f;
      float iB = pB[r] - nB[r];
      float sB = sqrtf(rB[r]*rB[r] + iB*iB);
      float eB = ((umB >> rowb) & 1u) ? __expf(sB) : 0.f;
      lsum[r] += eA + eB;
      unsigned pk = (unsigned)f2bf(eA) | ((unsigned)f2bf(eB) << 16);
      *(unsigned*)(elds + rowl*ESTRIDE + grp*64 + col*4) = pk;
    }
  }

  // ---- row-sum reduce -> linv ----
  #pragma unroll
  for (int r = 0; r < 4; r++){
    float v = lsum[r];
    v += __shfl_xor(v, 1); v += __shfl_xor(v, 2);
    v += __shfl_xor(v, 4); v += __shfl_xor(v, 8);
    if (col == 0) l_red[w][kg*4 + r] = v;
  }
  __syncthreads();
  if (tid < BQ2){
    float s = 0.f;
    #pragma unroll
    for (int ww = 0; ww < 8; ww++) s += l_red[ww][tid];
    linv_lds[tid] = 1.f / s;
  }
  __syncthreads();

  // ---- Phase B: PV from e-LDS; wave w -> ri = w>>2, dg = w&3 ----
  {
    int ri = w >> 2;
    int dg = w & 3;
    const unsigned short* vbase = vf + ((size_t)(ri*NBH + bh)*4 + dg) * 64*64*8;
    f32x4 acc = (f32x4)(0.f);
    for (int win = 0; win < 64; win++){
      short8 bv = *(const short8*)(vbase + ((size_t)win*64 + lane)*8);
      short8 a  = *(const short8*)(elds + col*ESTRIDE + win*64 + kg*16);
      acc = __builtin_amdgcn_mfma_f32_16x16x32_bf16(a, bv, acc, 0, 0, 0);
    }
    float* outp = out + (ri ? OUTSZ : 0) + bhSD;
    #pragma unroll
    for (int r = 0; r < 4; r++){
      int row = kg*4 + r;
      outp[(size_t)(qbase + row) * D + dg*16 + col] = acc[r] * linv_lds[row];
    }
  }

  // ---- Phase C: attn = e * linv; linear LDS reads, coalesced float2 stores ----
  {
    float* attnp = out + 2*OUTSZ + (size_t)bh*S*S + (size_t)qbase*S;
    #pragma unroll 4
    for (int it = 0; it < 32; it++){
      int p   = it*512 + tid;                        // pair index, 16*1024 total
      int row = p >> 10;
      int po  = p & 1023;
      unsigned pk = *(const unsigned*)(elds + row*ESTRIDE + po*4);
      float inv = linv_lds[row];
      float2 o;
      o.x = bf2f((unsigned short)(pk & 0xffffu)) * inv;
      o.y = bf2f((unsigned short)(pk >> 16))     * inv;
      *(float2*)(attnp + (size_t)row*S + 2*po) = o;
    }
  }
}

// ---------------- tier-3: no-workspace fallback (round-2 kernel, proven) ----------
__global__ __launch_bounds__(512) void cattn_kernel(
    const float* __restrict__ q_real, const float* __restrict__ q_imag,
    const float* __restrict__ k_real, const float* __restrict__ k_imag,
    const float* __restrict__ v_real, const float* __restrict__ v_imag,
    const int*   __restrict__ mask,   float* __restrict__ out)
{
  extern __shared__ __align__(16) char lds[];
  float* l_lds = (float*)(lds + (size_t)BQ*S*2);
  float* l_inv = l_lds + 8*BQ;

  int bid = blockIdx.x;
  int swz = (bid & 7) * (NBLK/8) + (bid >> 3);
  int bh    = swz / QT;
  int qt    = swz % QT;
  int b0    = bh / NH;
  int qbase = qt * BQ;

  int tid  = threadIdx.x;
  int w    = tid >> 6;
  int lane = tid & 63;
  int col  = lane & 15;
  int kg   = lane >> 4;

  const size_t bhSD = (size_t)bh * S * D;

  short8 a_r[2][4], a_i[2][4];
  #pragma unroll
  for (int m = 0; m < 2; m++){
    const float* qrp = q_real + bhSD + (size_t)(qbase + m*16 + col) * D;
    const float* qip = q_imag + bhSD + (size_t)(qbase + m*16 + col) * D;
    #pragma unroll
    for (int h = 0; h < 2; h++){
      int d0 = h*32 + kg*8;
      float4 r0 = *(const float4*)(qrp + d0);
      float4 r1 = *(const float4*)(qrp + d0 + 4);
      float4 i0 = *(const float4*)(qip + d0);
      float4 i1 = *(const float4*)(qip + d0 + 4);
      a_r[m][h]   = pack8(r0, r1,  0.125f);
      a_r[m][2+h] = pack8(i0, i1,  0.125f);
      a_i[m][h]   = a_r[m][2+h];
      a_i[m][2+h] = pack8(r0, r1, -0.125f);
    }
  }

  float lsum[2][4] = {{0.f,0.f,0.f,0.f},{0.f,0.f,0.f,0.f}};
  const int* mrow = mask + (size_t)b0 * S * S;

  for (int t = 0; t < 16; t++){
    int key = w*256 + t*16 + col;
    const float* krp = k_real + bhSD + (size_t)key * D;
    const float* kip = k_imag + bhSD + (size_t)key * D;
    short8 bv[4];
    #pragma unroll
    for (int h = 0; h < 2; h++){
      int d0 = h*32 + kg*8;
      float4 r0 = *(const float4*)(krp + d0);
      float4 r1 = *(const float4*)(krp + d0 + 4);
      float4 i0 = *(const float4*)(kip + d0);
      float4 i1 = *(const float4*)(kip + d0 + 4);
      bv[h]   = pack8(r0, r1, 1.f);
      bv[2+h] = pack8(i0, i1, 1.f);
    }
    f32x4 accr[2], acci[2];
    #pragma unroll
    for (int m = 0; m < 2; m++){ accr[m] = (f32x4)(0.f); acci[m] = (f32x4)(0.f); }
    #pragma unroll
    for (int m = 0; m < 2; m++)
      #pragma unroll
      for (int kc = 0; kc < 4; kc++){
        accr[m] = __builtin_amdgcn_mfma_f32_16x16x32_bf16(a_r[m][kc], bv[kc], accr[m], 0, 0, 0);
        acci[m] = __builtin_amdgcn_mfma_f32_16x16x32_bf16(a_i[m][kc], bv[kc], acci[m], 0, 0, 0);
      }
    #pragma unroll
    for (int m = 0; m < 2; m++){
      int qrow_g = qbase + m*16 + kg*4;
      #pragma unroll
      for (int r = 0; r < 4; r++){
        float ar = accr[m][r], ai = acci[m][r];
        float s  = sqrtf(ar*ar + ai*ai);
        int  mv  = mrow[(size_t)(qrow_g + r) * S + key];
        float ex = __expf(s);
        float e  = mv ? ex : 0.f;
        lsum[m][r] += e;
        *(unsigned short*)(lds + eoff(m*16 + kg*4 + r, key)) = f2bf(e);
      }
    }
  }

  #pragma unroll
  for (int m = 0; m < 2; m++)
    #pragma unroll
    for (int r = 0; r < 4; r++){
      float v = lsum[m][r];
      v += __shfl_xor(v, 1); v += __shfl_xor(v, 2);
      v += __shfl_xor(v, 4); v += __shfl_xor(v, 8);
      lsum[m][r] = v;
    }
  if (col == 0){
    #pragma unroll
    for (int m = 0; m < 2; m++)
      #pragma unroll
      for (int r = 0; r < 4; r++)
        l_lds[w*BQ + m*16 + kg*4 + r] = lsum[m][r];
  }
  __syncthreads();
  if (tid < BQ){
    float t = 0.f;
    #pragma unroll
    for (int ww = 0; ww < 8; ww++) t += l_lds[ww*BQ + tid];
    l_inv[tid] = 1.f / t;
  }
  __syncthreads();

  {
    int ri    = w >> 2;
    int dbase = (w & 3) * 16;
    const float* vp = (ri ? v_imag : v_real) + bhSD;
    f32x4 acc[2]; acc[0] = (f32x4)(0.f); acc[1] = (f32x4)(0.f);
    for (int c = 0; c < 64; c++){
      int k0 = c*32 + kg*8;
      short8 bv;
      #pragma unroll
      for (int j = 0; j < 8; j++)
        bv[j] = (short)f2bf(vp[(size_t)(k0 + j) * D + dbase + col]);
      #pragma unroll
      for (int m = 0; m < 2; m++){
        short8 av = *(const short8*)(lds + eoff(m*16 + col, k0));
        acc[m] = __builtin_amdgcn_mfma_f32_16x16x32_bf16(av, bv, acc[m], 0, 0, 0);
      }
    }
    float* outp = out + (ri ? OUTSZ : 0) + bhSD;
    #pragma unroll
    for (int m = 0; m < 2; m++)
      #pragma unroll
      for (int r = 0; r < 4; r++){
        int row = m*16 + kg*4 + r;
        outp[(size_t)(qbase + row) * D + dbase + col] = acc[m][r] * l_inv[row];
      }
  }

  {
    float* attnp = out + 2*OUTSZ + (size_t)bh*S*S + (size_t)qbase*S;
    #pragma unroll
    for (int g = 0; g < 16; g++){
      int flat = g*4096 + tid*8;
      int row  = flat >> 11;
      int k    = flat & 2047;
      short8 ev = *(const short8*)(lds + eoff(row, k));
      float inv = l_inv[row];
      float4 o0, o1;
      o0.x = bf2f((unsigned short)ev[0]) * inv;
      o0.y = bf2f((unsigned short)ev[1]) * inv;
      o0.z = bf2f((unsigned short)ev[2]) * inv;
      o0.w = bf2f((unsigned short)ev[3]) * inv;
      o1.x = bf2f((unsigned short)ev[4]) * inv;
      o1.y = bf2f((unsigned short)ev[5]) * inv;
      o1.z = bf2f((unsigned short)ev[6]) * inv;
      o1.w = bf2f((unsigned short)ev[7]) * inv;
      *(float4*)(attnp + (size_t)row*S + k)     = o0;
      *(float4*)(attnp + (size_t)row*S + k + 4) = o1;
    }
  }
}

extern "C" void kernel_launch(void* const* d_in, const int* in_sizes, int n_in,
                              void* d_out, int out_size, void* d_ws, size_t ws_size,
                              hipStream_t stream)
{
  const float* qr = (const float*)d_in[0];
  const float* qi = (const float*)d_in[1];
  const float* kr = (const float*)d_in[2];
  const float* ki = (const float*)d_in[3];
  const float* vr = (const float*)d_in[4];
  const float* vi = (const float*)d_in[5];
  const int*   mk = (const int*)d_in[6];
  float* out = (float*)d_out;

  if (ws_size >= WS_NEED){
    unsigned short* kf = (unsigned short*)((char*)d_ws + KF_OFF);
    unsigned short* vf = (unsigned short*)((char*)d_ws + VF_OFF);
    unsigned*       mq = (unsigned*)((char*)d_ws + MQ_OFF);
    conv_k<<<dim3(3072),     dim3(256), 0, stream>>>(kr, ki, kf);
    conv_v<<<dim3(2*NBH*32), dim3(256), 0, stream>>>(vr, vi, vf);
    conv_m<<<dim3(NB*QT),    dim3(256), 0, stream>>>(mk, mq);
    cattn_merged<<<dim3(NBLK2), dim3(512), 0, stream>>>(qr, qi, kf, vf, mq, out);
  } else {
    size_t ldsb = (size_t)BQ*S*2 + (size_t)8*BQ*4 + (size_t)BQ*4;
    cattn_kernel<<<dim3(NBLK), dim3(512), ldsb, stream>>>(qr, qi, kr, ki, vr, vi, mk, out);
  }
}